// Round 13
// baseline (318.930 us; speedup 1.0000x reference)
//
#include <hip/hip_runtime.h>
#include <math.h>

// ---------------------------------------------------------------------------
// GCN 2-layer forward on MI355X.
// Round 24: L2-pinned gathers via REAL XCC_ID + parity work-queue.
// Gather model (R14-R23 invariant): rate = MSHR/CU (~30) / latency (~600cy
// L3) = 0.05 CL/cy/CU -> 30G random CL/s chip. Only lever left: cut latency
// by making each XCD's random working set L2-resident. Each block reads its
// XCD via s_getreg(HW_REG_XCC_ID) [m09], pops (half = xcd&1) work from an
// atomic parity queue (steal on exhaust -> full coverage regardless of
// scheduler drift - the flaw that nulled R20's blockIdx%8 pinning). Even
// XCDs touch only the low 64 columns (3.2 MB < 4 MiB L2), odd the high.
// Layer-2 split: k_ag2 (half-col gather -> bf16 agg2) + k_gemm2s
// (GEMM + b2 + sigmoid), since the fused MFMA needs full K=128 rows.
// Numerics: same accumulation order/rounding as R21/R23 -> absmax unchanged.
// ---------------------------------------------------------------------------

typedef unsigned int uint32;
typedef unsigned long long u64;
typedef __attribute__((ext_vector_type(8))) short bf16x8;   // 8 bf16 (4 VGPRs)
typedef __attribute__((ext_vector_type(4))) float f32x4;
typedef __attribute__((ext_vector_type(2))) float f32x2;

__device__ __forceinline__ unsigned short f2bf(float f) {   // RNE fp32->bf16
    uint32 b = __float_as_uint(f);
    return (unsigned short)((b + 0x7FFFu + ((b >> 16) & 1u)) >> 16);
}

// ---------------------------------------------------------------------------
// MFMA GEMM body: H[n x 128] = A[n x 128] @ W (WT bf16 transposed).
// 256 threads = 4 waves; each wave 32 rows x 128 cols (2x8 16x16 tiles),
// K=128 in 4 steps. AFP32: A fp32 (converted inline) vs bf16.
// OUTFP8: D written as fp8 e4m3 bytes vs bf16.
// ---------------------------------------------------------------------------
template <int AFP32, int OUTFP8>
__device__ __forceinline__ void gemm_body(const void* __restrict__ Ap,
                                          const unsigned short* __restrict__ WT,
                                          void* __restrict__ H,
                                          int n, int tb) {
    const int lane = threadIdx.x & 63;
    const int wv   = threadIdx.x >> 6;
    const int quad = lane >> 4;
    const int l16  = lane & 15;
    const int m0   = tb * 128 + wv * 32;
    f32x4 acc[2][8] = {};

    #pragma unroll
    for (int ks = 0; ks < 4; ++ks) {
        const int k0 = ks * 32 + quad * 8;
        bf16x8 a[2];
        #pragma unroll
        for (int rt = 0; rt < 2; ++rt) {
            int row = m0 + rt * 16 + l16;
            if (row >= n) row = n - 1;  // clamp; stores are guarded
            if (AFP32) {
                const float* Af = (const float*)Ap + (size_t)row * 128 + k0;
                float4 f0 = *(const float4*)(Af);
                float4 f1 = *(const float4*)(Af + 4);
                bf16x8 v;
                v[0] = (short)f2bf(f0.x); v[1] = (short)f2bf(f0.y);
                v[2] = (short)f2bf(f0.z); v[3] = (short)f2bf(f0.w);
                v[4] = (short)f2bf(f1.x); v[5] = (short)f2bf(f1.y);
                v[6] = (short)f2bf(f1.z); v[7] = (short)f2bf(f1.w);
                a[rt] = v;
            } else {
                const unsigned short* Ab = (const unsigned short*)Ap + (size_t)row * 128 + k0;
                a[rt] = *(const bf16x8*)Ab;
            }
        }
        #pragma unroll
        for (int ct = 0; ct < 8; ++ct) {
            bf16x8 b = *(const bf16x8*)(WT + (size_t)(ct * 16 + l16) * 128 + k0);
            acc[0][ct] = __builtin_amdgcn_mfma_f32_16x16x32_bf16(a[0], b, acc[0][ct], 0, 0, 0);
            acc[1][ct] = __builtin_amdgcn_mfma_f32_16x16x32_bf16(a[1], b, acc[1][ct], 0, 0, 0);
        }
    }

    // D layout: col = lane&15, row = quad*4 + reg  (m89-verified)
    #pragma unroll
    for (int rt = 0; rt < 2; ++rt) {
        #pragma unroll
        for (int r = 0; r < 4; ++r) {
            int row = m0 + rt * 16 + quad * 4 + r;
            if (row < n) {
                if (OUTFP8) {
                    unsigned char* o = (unsigned char*)H + (size_t)row * 128 + l16;
                    #pragma unroll
                    for (int cp = 0; cp < 4; ++cp) {
                        int pk = __builtin_amdgcn_cvt_pk_fp8_f32(
                            acc[rt][2 * cp][r], acc[rt][2 * cp + 1][r], 0, false);
                        o[(2 * cp) * 16]     = (unsigned char)(pk & 0xFF);
                        o[(2 * cp + 1) * 16] = (unsigned char)((pk >> 8) & 0xFF);
                    }
                } else {
                    unsigned short* o = (unsigned short*)H + (size_t)row * 128 + l16;
                    #pragma unroll
                    for (int ct = 0; ct < 8; ++ct)
                        o[ct * 16] = f2bf(acc[rt][ct][r]);
                }
            }
        }
    }
}

// ---------------------------------------------------------------------------
// Init (64 blocks): done counter + parity queue counters + 16 csr pad
// entries + transpose/convert W1/W2 to bf16. packed[] zeroed by blit memset.
// ---------------------------------------------------------------------------
__global__ __launch_bounds__(256) void k_init(int* __restrict__ done,
                                              int* __restrict__ qctr,
                                              float2* __restrict__ csr, int E,
                                              const float* __restrict__ W1,
                                              const float* __restrict__ W2,
                                              unsigned short* __restrict__ WT1,
                                              unsigned short* __restrict__ WT2) {
    int idx = blockIdx.x * 256 + threadIdx.x;
    if (idx == 0) *done = 0;
    if (idx < 4) qctr[idx] = 0;
    if (idx < 16) csr[E + idx] = make_float2(0.0f, 0.0f);  // pad: row 0, w 0
    int k = idx >> 7, nn = idx & 127;   // 16384 total
    WT1[nn * 128 + k] = f2bf(W1[k * 128 + nn]);
    WT2[nn * 128 + k] = f2bf(W2[k * 128 + nn]);
}

// ---------------------------------------------------------------------------
// Fused gemm1 + hist: blocks [0,gGemm) compute h8 = fp8(x@W1) (MFMA pipe);
// blocks [gGemm, ...) do the 8-replica u64 histogram (atomic/TCC pipe).
// Replica r = (i>>8)&7, rank[i] = per-replica arrival order (atomic return).
// ---------------------------------------------------------------------------
__global__ __launch_bounds__(256) void k_gemm1_hist(const float* __restrict__ x,
                                                    const unsigned short* __restrict__ WT1,
                                                    unsigned char* __restrict__ h8,
                                                    const int* __restrict__ dst,
                                                    const float* __restrict__ ew,
                                                    u64* __restrict__ packed,
                                                    int* __restrict__ rank,
                                                    int E, int N, int gGemm) {
    const int b = blockIdx.x;
    if (b < gGemm) {
        gemm_body<1, 1>(x, WT1, h8, N, b);
        return;
    }
    int i = (b - gGemm) * 256 + threadIdx.x;
    if (i < E) {
        int d = dst[i];
        int r = (i >> 8) & 7;
        u64 add = (1ULL << 44) + (u64)(ew[i] * 4294967296.0f);
        u64 old = atomicAdd(&packed[(size_t)r * N + d], add);
        rank[i] = (int)(old >> 44);
    }
}

// ---------------------------------------------------------------------------
// Scan (one kernel): per-1024-chunk local exclusive scan of total counts into
// rowptr, fused decode (dinv, 8x8-bit replica bases), chunk totals release-
// stored into csums; last block (done counter) wave-scans the <=64 totals
// into exclusive chunk offsets in place.
// ---------------------------------------------------------------------------
__global__ __launch_bounds__(256) void k_scan(const u64* __restrict__ packed,
                                              float* __restrict__ dinv,
                                              u64* __restrict__ bases,
                                              int* __restrict__ rowptr,
                                              int* __restrict__ csums,
                                              int* __restrict__ done, int nNodes) {
    __shared__ int s[256];
    __shared__ int lastFlag;
    const int t = threadIdx.x;
    const int base = blockIdx.x * 1024 + t * 4;
    const int n = nNodes + 1;  // scan domain: N counts + trailing 0
    int v[4];
    #pragma unroll
    for (int u = 0; u < 4; ++u) {
        int idx = base + u;
        int c = 0;
        if (idx < nNodes) {
            const u64 mask = (1ULL << 44) - 1;
            u64 ssum = 0;
            u64 bs = 0;
            uint32 cum = 0;
            #pragma unroll
            for (int r = 0; r < 8; ++r) {
                u64 pv = packed[(size_t)r * nNodes + idx];
                bs |= (u64)cum << (8 * r);  // field 0 = 0
                cum += (uint32)(pv >> 44);
                ssum += (pv & mask);
            }
            c = (int)cum;
            float deg = 1.0f + (float)ssum * (1.0f / 4294967296.0f);
            dinv[idx] = rsqrtf(deg);
            bases[idx] = bs;
        }
        v[u] = c;
    }
    s[t] = v[0] + v[1] + v[2] + v[3];
    __syncthreads();
    #pragma unroll
    for (int off = 1; off < 256; off <<= 1) {
        int x = (t >= off) ? s[t - off] : 0;
        __syncthreads();
        s[t] += x;
        __syncthreads();
    }
    if (t == 255)
        __hip_atomic_store(&csums[blockIdx.x], s[255], __ATOMIC_RELEASE,
                           __HIP_MEMORY_SCOPE_AGENT);
    int e = (t == 0) ? 0 : s[t - 1];
    if (base + 0 < n) rowptr[base + 0] = e;
    if (base + 1 < n) rowptr[base + 1] = e + v[0];
    if (base + 2 < n) rowptr[base + 2] = e + v[0] + v[1];
    if (base + 3 < n) rowptr[base + 3] = e + v[0] + v[1] + v[2];

    // last-block: exclusive scan of the gridDim.x (<=64) chunk totals
    __syncthreads();  // all stores issued (incl. t255's release store)
    if (t == 0) {
        int prev = __hip_atomic_fetch_add(done, 1, __ATOMIC_ACQ_REL,
                                          __HIP_MEMORY_SCOPE_AGENT);
        lastFlag = (prev == (int)gridDim.x - 1);
    }
    __syncthreads();
    if (lastFlag && t < 64) {
        int g = (int)gridDim.x;
        int orig = (t < g) ? __hip_atomic_load(&csums[t], __ATOMIC_ACQUIRE,
                                               __HIP_MEMORY_SCOPE_AGENT)
                           : 0;
        int vv = orig;
        #pragma unroll
        for (int off = 1; off < 64; off <<= 1) {
            int y = __shfl_up(vv, off, 64);
            if (t >= off) vv += y;
        }
        if (t < g) csums[t] = vv - orig;  // exclusive chunk offset
    }
}

// Fill CSR (atomic-free):
//   pos = rowptr_local[d] + csums[d>>10] + base_replica(d, r) + rank[e].
// csr.x stores src*16 (uint2-row offset) to shave gather address math.
__global__ __launch_bounds__(256) void k_fill(const int* __restrict__ src,
                                              const int* __restrict__ dst,
                                              const float* __restrict__ ew,
                                              const float* __restrict__ dinv,
                                              const int* __restrict__ rowptr,
                                              const int* __restrict__ csums,
                                              const u64* __restrict__ bases,
                                              const int* __restrict__ rank,
                                              float2* __restrict__ csr, int e) {
    int i = blockIdx.x * 256 + threadIdx.x;
    if (i < e) {
        int s = src[i], d = dst[i];
        int r = (i >> 8) & 7;  // must match k_gemm1_hist's replica map
        float nrm = dinv[s] * ew[i] * dinv[d];
        int pos = rowptr[d] + csums[d >> 10]
                + (int)((bases[d] >> (8 * r)) & 0xFF) + rank[i];
        csr[pos] = make_float2(__int_as_float(s << 4), nrm);
    }
}

// ---------------------------------------------------------------------------
// Half-row gather primitives: each lane covers 4 columns (one dword of fp8).
// ---------------------------------------------------------------------------
__device__ __forceinline__ void fma4_f8(float* acc, uint32 u, float w) {
    f32x2 f;
    f = __builtin_amdgcn_cvt_pk_f32_fp8((int)u, false);
    acc[0] += f[0] * w; acc[1] += f[1] * w;
    f = __builtin_amdgcn_cvt_pk_f32_fp8((int)u, true);
    acc[2] += f[0] * w; acc[3] += f[1] * w;
}

// Per-quarter half-row edge walk, software-pipelined (csr padded past E,
// csr.x pre-scaled src*16 -> dword index = (x<<1)+cbase).
__device__ __forceinline__ void gather_h8p(float* acc, const uint32* __restrict__ T,
                                           const float2* __restrict__ csr,
                                           int start, int end, int cbase) {
    float2 c[8];
    #pragma unroll
    for (int j = 0; j < 8; ++j) c[j] = csr[start + j];   // padded-safe
    for (int k = start; k < end; k += 8) {
        uint32 u[8];
        float w[8];
        float2 cn[8];
        #pragma unroll
        for (int j = 0; j < 8; ++j) {
            w[j] = (k + j < end) ? c[j].y : 0.0f;
            u[j] = T[(((size_t)(uint32)__float_as_int(c[j].x)) << 1) + cbase];
        }
        #pragma unroll
        for (int j = 0; j < 8; ++j) cn[j] = csr[k + 8 + j];   // prefetch
        #pragma unroll
        for (int j = 0; j < 8; ++j) fma4_f8(acc, u[j], w[j]);
        #pragma unroll
        for (int j = 0; j < 8; ++j) c[j] = cn[j];
    }
}

// Pop one (half, group) work item: own parity first, steal on exhaust.
// Guarantees every (half, group) claimed exactly once when grid = 2*ngroups.
__device__ __forceinline__ void pop_work(int* __restrict__ qctr, int ngroups,
                                         int* sH, int* sG) {
    if (threadIdx.x == 0) {
        uint32 xcc;
        asm volatile("s_getreg_b32 %0, hwreg(HW_REG_XCC_ID)" : "=s"(xcc));
        int h = (int)(xcc & 1u);
        int g = atomicAdd(&qctr[h], 1);
        if (g >= ngroups) { h ^= 1; g = atomicAdd(&qctr[h], 1); }
        *sH = h; *sG = g;
    }
    __syncthreads();
}

// ---------------------------------------------------------------------------
// Layer-1 aggregation, L2-pinned: g8 = fp8(relu(agg(h8) + b1)).
// Work item = (half, 16-node group); quarter-per-node; each lane covers 4
// cols of its half. Even XCDs stay in the low 3.2 MB half-table (fits L2).
// ---------------------------------------------------------------------------
__global__ __launch_bounds__(256) void k_ag1(const unsigned char* __restrict__ h8,
                                             const float2* __restrict__ csr,
                                             const int* __restrict__ rowptr,
                                             const int* __restrict__ csums,
                                             const float* __restrict__ dinv,
                                             const float4* __restrict__ bias4,
                                             unsigned char* __restrict__ g8,
                                             int* __restrict__ qctr,
                                             int ngroups, int N) {
    __shared__ int sH, sG;
    pop_work(qctr, ngroups, &sH, &sG);
    const int half = sH, grp = sG;
    if (grp >= ngroups) return;   // uniform
    const int lane = threadIdx.x & 63;
    const int q = lane >> 4, l = lane & 15;
    const int node = grp * 16 + (threadIdx.x >> 6) * 4 + q;
    if (node >= N) return;   // lane-divergent ok: no barriers below
    const uint32* H1 = (const uint32*)h8;   // row = 32 dwords
    const int cbase = half * 16 + l;
    const int start = rowptr[node] + csums[node >> 10];
    const int end   = rowptr[node + 1] + csums[(node + 1) >> 10];
    const float di = dinv[node];

    float acc[4] = {};
    fma4_f8(acc, H1[(size_t)node * 32 + cbase], di * di);   // self-loop
    gather_h8p(acc, H1, csr, start, end, cbase);

    float4 bb = bias4[cbase];   // cols [cbase*4, cbase*4+4)
    acc[0] += bb.x; acc[1] += bb.y; acc[2] += bb.z; acc[3] += bb.w;
    #pragma unroll
    for (int j = 0; j < 4; ++j) acc[j] = fmaxf(acc[j], 0.0f);
    int w0 = __builtin_amdgcn_cvt_pk_fp8_f32(acc[0], acc[1], 0, false);
    w0     = __builtin_amdgcn_cvt_pk_fp8_f32(acc[2], acc[3], w0, true);
    ((uint32*)g8)[(size_t)node * 32 + cbase] = (uint32)w0;
}

// ---------------------------------------------------------------------------
// Layer-2 aggregation, L2-pinned: agg2 = bf16(agg(g8)) [N][128].
// Same structure as k_ag1, no bias/act; bf16 out feeds k_gemm2s.
// ---------------------------------------------------------------------------
__global__ __launch_bounds__(256) void k_ag2(const unsigned char* __restrict__ g8,
                                             const float2* __restrict__ csr,
                                             const int* __restrict__ rowptr,
                                             const int* __restrict__ csums,
                                             const float* __restrict__ dinv,
                                             unsigned short* __restrict__ agg2,
                                             int* __restrict__ qctr,
                                             int ngroups, int N) {
    __shared__ int sH, sG;
    pop_work(qctr, ngroups, &sH, &sG);
    const int half = sH, grp = sG;
    if (grp >= ngroups) return;   // uniform
    const int lane = threadIdx.x & 63;
    const int q = lane >> 4, l = lane & 15;
    const int node = grp * 16 + (threadIdx.x >> 6) * 4 + q;
    if (node >= N) return;
    const uint32* G1 = (const uint32*)g8;
    const int cbase = half * 16 + l;
    const int start = rowptr[node] + csums[node >> 10];
    const int end   = rowptr[node + 1] + csums[(node + 1) >> 10];
    const float di = dinv[node];

    float acc[4] = {};
    fma4_f8(acc, G1[(size_t)node * 32 + cbase], di * di);   // self-loop
    gather_h8p(acc, G1, csr, start, end, cbase);

    uint2 o;
    o.x = (uint32)f2bf(acc[0]) | ((uint32)f2bf(acc[1]) << 16);
    o.y = (uint32)f2bf(acc[2]) | ((uint32)f2bf(acc[3]) << 16);
    ((uint2*)agg2)[(size_t)node * 32 + cbase] = o;
}

// ---------------------------------------------------------------------------
// Layer-2 GEMM + bias + sigmoid: out = sigmoid(agg2 @ W2 + b2), fp32 out.
// Same tiling as gemm_body (4 waves x 32 rows x 128 cols, K=128).
// ---------------------------------------------------------------------------
__global__ __launch_bounds__(256) void k_gemm2s(const unsigned short* __restrict__ A,
                                                const unsigned short* __restrict__ WT2,
                                                const float* __restrict__ b2,
                                                float* __restrict__ out, int n) {
    const int lane = threadIdx.x & 63;
    const int wv   = threadIdx.x >> 6;
    const int quad = lane >> 4;
    const int l16  = lane & 15;
    const int m0   = blockIdx.x * 128 + wv * 32;
    f32x4 acc[2][8] = {};

    #pragma unroll
    for (int ks = 0; ks < 4; ++ks) {
        const int k0 = ks * 32 + quad * 8;
        bf16x8 a[2];
        #pragma unroll
        for (int rt = 0; rt < 2; ++rt) {
            int row = m0 + rt * 16 + l16;
            if (row >= n) row = n - 1;  // clamp; stores are guarded
            a[rt] = *(const bf16x8*)(A + (size_t)row * 128 + k0);
        }
        #pragma unroll
        for (int ct = 0; ct < 8; ++ct) {
            bf16x8 b = *(const bf16x8*)(WT2 + (size_t)(ct * 16 + l16) * 128 + k0);
            acc[0][ct] = __builtin_amdgcn_mfma_f32_16x16x32_bf16(a[0], b, acc[0][ct], 0, 0, 0);
            acc[1][ct] = __builtin_amdgcn_mfma_f32_16x16x32_bf16(a[1], b, acc[1][ct], 0, 0, 0);
        }
    }

    // D layout: col = lane&15 (within ct tile), row = quad*4 + reg
    #pragma unroll
    for (int rt = 0; rt < 2; ++rt) {
        #pragma unroll
        for (int r = 0; r < 4; ++r) {
            int row = m0 + rt * 16 + quad * 4 + r;
            if (row < n) {
                #pragma unroll
                for (int ct = 0; ct < 8; ++ct) {
                    int col = ct * 16 + l16;
                    float v = acc[rt][ct][r] + b2[col];
                    out[(size_t)row * 128 + col] = 1.0f / (1.0f + expf(-v));
                }
            }
        }
    }
}

extern "C" void kernel_launch(void* const* d_in, const int* in_sizes, int n_in,
                              void* d_out, int out_size, void* d_ws, size_t ws_size,
                              hipStream_t stream) {
    const float* x  = (const float*)d_in[0];
    const int*   ei = (const int*)d_in[1];
    const float* ew = (const float*)d_in[2];
    const float* W1 = (const float*)d_in[3];
    const float* b1 = (const float*)d_in[4];
    const float* W2 = (const float*)d_in[5];
    const float* b2 = (const float*)d_in[6];

    const int N = in_sizes[0] / 128;
    const int E = in_sizes[2];
    const int* src = ei;
    const int* dst = ei + E;
    float* out = (float*)d_out;

    // Workspace layout (256B-aligned slabs):
    //   dinv [N] | rowptr [N+1] | csums [1024] | done | qctr[4] | bases [N u64]
    //   | WT1 | WT2 | csr [E+16 f2] | g8 [N*128 fp8] | h8 [N*128 fp8]
    //   | rank [E]
    //   Aliases: packed u64[8N] = g8 slab (dead after scan; g8 written at ag1).
    //            agg2 bf16[N*128] = h8 slab onward (h8 dead after ag1, rank
    //            dead after fill; 12.8 MB = h8 6.4 + rank 2.4 + 4.0 tail).
    auto align = [](size_t v) { return (v + 255) & ~(size_t)255; };
    char* p = (char*)d_ws;
    float*  dinv   = (float*)p;   p += align((size_t)N * 4);
    int*    rowptr = (int*)p;     p += align((size_t)(N + 1) * 4);
    int*    csums  = (int*)p;     p += align((size_t)1024 * 4);
    int*    done   = (int*)p;     p += align((size_t)256);
    int*    qctr   = (int*)p;     p += align((size_t)256);
    u64*    bases  = (u64*)p;     p += align((size_t)N * 8);
    unsigned short* WT1 = (unsigned short*)p; p += align((size_t)128 * 128 * 2);
    unsigned short* WT2 = (unsigned short*)p; p += align((size_t)128 * 128 * 2);
    float2* csr    = (float2*)p;  p += align((size_t)(E + 16) * 8);
    unsigned char*  g8 = (unsigned char*)p;  p += align((size_t)N * 128);
    unsigned char*  h8 = (unsigned char*)p;  // h8 slab start
    unsigned short* agg2 = (unsigned short*)h8;  // alias: h8+rank+tail (12.8 MB)
    p += align((size_t)N * 128);
    int*    rank   = (int*)p;     p += align((size_t)E * 4);
    u64* packed = (u64*)g8;  // alias (dead after scan; g8 written at ag1)

    const int nbE = (E + 255) / 256;
    const int gScan = (N + 1 + 1023) / 1024;   // 49 for N=50000 (<=64 required)
    const int gGemm = (N + 127) / 128;
    const int ngroups = (N + 15) / 16;         // 3125
    const int gAgg = 2 * ngroups;              // both column halves

    // --- Build (+ layer-1 GEMM overlapped with hist) ---
    hipMemsetAsync(packed, 0, (size_t)N * 8 * 8, stream);   // blit-engine zero
    k_init<<<64, 256, 0, stream>>>(done, qctr, csr, E, W1, W2, WT1, WT2);
    k_gemm1_hist<<<gGemm + nbE, 256, 0, stream>>>(x, WT1, h8, dst, ew, packed,
                                                  rank, E, N, gGemm);
    k_scan<<<gScan, 256, 0, stream>>>(packed, dinv, bases, rowptr, csums, done, N);
    k_fill<<<nbE, 256, 0, stream>>>(src, dst, ew, dinv, rowptr, csums, bases,
                                    rank, csr, E);

    // --- Layer 1: g8 = fp8(relu(agg(h8) + b1)), L2-pinned halves ---
    k_ag1<<<gAgg, 256, 0, stream>>>(h8, csr, rowptr, csums, dinv,
                                    (const float4*)b1, g8, qctr, ngroups, N);

    // --- Layer 2: agg2 = bf16(agg(g8)) (L2-pinned) ; out = sigmoid(agg2@W2+b2) ---
    k_ag2<<<gAgg, 256, 0, stream>>>(g8, csr, rowptr, csums, dinv, agg2,
                                    qctr + 2, ngroups, N);
    k_gemm2s<<<gGemm, 256, 0, stream>>>(agg2, WT2, b2, out, N);
}